// Round 1
// 209.136 us; speedup vs baseline: 1.0025x; 1.0025x over previous
//
#include <hip/hip_runtime.h>

// LatticeCrf log_prob on MI355X — MFMA chunked linear-space scan, v5.
// v5: replace per-thread register staging (s[2][16], 128 scalar global loads
// per thread) with async global_load_lds double-buffering: each wave DMAs its
// next 4KB score matrix into a private LDS buffer (4x dwordx4, 1KB/instr,
// zero VGPR cost), counted s_waitcnt vmcnt(4) keeps the next matrix in flight
// across the whole step (never drain in-loop). Frees ~32 VGPRs under the
// __launch_bounds__(256,4) 128-VGPR cap and decouples HBM latency from the
// MFMA dependency chain. Stage buffers are reused as the combine pbuf.
#define BB 64
#define TT 512
#define VV 32
#define CC 64           // chunks per sequence
#define L  8            // steps per chunk
#define QPB 4           // chunks per block (tree-combined)
#define NMAT (CC/QPB)   // 16 combined matrices per b
#define PSTR 34         // LDS pad stride for combine pbuf
#define LOG2E 1.4426950408889634f
#define LN2f  0.6931471805599453f
#define SHIFT 6.0f

typedef __bf16 bf16x8 __attribute__((ext_vector_type(8)));
typedef float  f32x16 __attribute__((ext_vector_type(16)));
union Frag { unsigned int u[4]; bf16x8 v; };

// round-half-up fp32->bf16 (inputs positive finite), pack two into one dword
__device__ __forceinline__ unsigned int pack_bf16(float lo, float hi) {
    unsigned int a = __float_as_uint(lo) + 0x8000u;
    unsigned int b = __float_as_uint(hi) + 0x8000u;
    return __builtin_amdgcn_perm(b, a, 0x07060302u); // [a.b2,a.b3,b.b2,b.b3]
}

// C-layout row for reg r / A-layout sigma for slot j: (x&3) + 8*(x>>2) + 4h
__device__ __forceinline__ int rowmap(int x, int h) {
    return (x & 3) + 8 * (x >> 2) + 4 * h;
}

// async global->LDS: 64 lanes x 16B = 1KB per instruction.
// LDS dest is wave-uniform base + lane*16 (hardware rule); global src is
// per-lane. Address-space pointers built via integer casts (low 32 bits of a
// generic LDS pointer are the LDS byte offset).
__device__ __forceinline__ void gload_lds_16(const void* g, const void* l) {
    __builtin_amdgcn_global_load_lds(
        (__attribute__((address_space(1))) void*)(uintptr_t)g,
        (__attribute__((address_space(3))) void*)(unsigned int)(uintptr_t)l,
        16, 0, 0);
}

// stage one 32x32 fp32 matrix (4KB, row-major, contiguous) into LDS linearly
__device__ __forceinline__ void stage_matrix(const float* g, float* l, int lane) {
#pragma unroll
    for (int i = 0; i < 4; ++i)
        gload_lds_16(g + i * 256 + lane * 4, l + i * 256);
}

// result = P_lds * accB   (A from LDS row-major stride PSTR, B = raw C-regs)
__device__ __forceinline__ f32x16 lds_mul(const float* P, int r, int h,
                                          const f32x16& accB) {
    Frag a1, a2, b1, b2;
#pragma unroll
    for (int p = 0; p < 4; ++p) {
        const int k1 = rowmap(2 * p, h);       // 0,2,8,10 (+4h)
        const int k2 = k1 + 16;
        const float2 x1 = *(const float2*)&P[r * PSTR + k1];
        const float2 x2 = *(const float2*)&P[r * PSTR + k2];
        a1.u[p] = pack_bf16(x1.x, x1.y);
        a2.u[p] = pack_bf16(x2.x, x2.y);
        b1.u[p] = pack_bf16(accB[2 * p],     accB[2 * p + 1]);
        b2.u[p] = pack_bf16(accB[8 + 2 * p], accB[8 + 2 * p + 1]);
    }
    f32x16 z;
#pragma unroll
    for (int i = 0; i < 16; ++i) z[i] = 0.f;
    f32x16 t = __builtin_amdgcn_mfma_f32_32x32x16_bf16(a1.v, b1.v, z, 0, 0, 0);
    return   __builtin_amdgcn_mfma_f32_32x32x16_bf16(a2.v, b2.v, t, 0, 0, 0);
}

__device__ __forceinline__ void lds_export(float* P, int m, int h,
                                           const f32x16& acc) {
#pragma unroll
    for (int r = 0; r < 16; ++r)
        P[rowmap(r, h) * PSTR + m] = acc[r];
}

__global__ __launch_bounds__(256, 4) void crf_chunk_fused(
    const float* __restrict__ scores,
    const int*   __restrict__ targets,
    const float* __restrict__ w_tx,
    const float* __restrict__ w_dur,
    float* __restrict__ ws_M,
    float* __restrict__ out)
{
    // per-wave double-buffered score matrices (4 waves x 2 x 4KB = 32KB);
    // aliased as the combine pbuf after the main loop (all stages drained).
    __shared__ float smem[QPB * 2 * 1024];
    __shared__ float w2s[VV * VV];

    const int tid  = threadIdx.x;
    const int lane = tid & 63;
    const int wid  = tid >> 6;
    const int m    = lane & 31;
    const int h    = lane >> 5;
    const int b    = blockIdx.x >> 4;
    const int q    = blockIdx.x & 15;
    const int c    = q * QPB + wid;

    // stage w2 = (w_tx + w_dur)*log2e - SHIFT into LDS (1024 entries)
    {
        const float4 wt = *(const float4*)(w_tx  + tid * 4);
        const float4 wd = *(const float4*)(w_dur + tid * 4);
        float4 r;
        r.x = (wt.x + wd.x) * LOG2E - SHIFT;
        r.y = (wt.y + wd.y) * LOG2E - SHIFT;
        r.z = (wt.z + wd.z) * LOG2E - SHIFT;
        r.w = (wt.w + wd.w) * LOG2E - SHIFT;
        *(float4*)&w2s[tid * 4] = r;
    }
    __syncthreads();   // drains the wt/wd loads; DMA stages issue after this

    float* S0 = smem + wid * 2048;   // wave-private buffer 0 (1024 floats)
    float* S1 = S0 + 1024;           // wave-private buffer 1

    const float* gbase = scores + ((size_t)b * TT + (size_t)c * L) * 1024;

    // prologue: t0 -> S0, t1 -> S1 (8 global_load_lds in flight)
    stage_matrix(gbase,        S0, lane);
    stage_matrix(gbase + 1024, S1, lane);

    float w2[16];
#pragma unroll
    for (int j = 0; j < 16; ++j)
        w2[j] = w2s[rowmap(j, h) * VV + m];

    f32x16 acc;
#pragma unroll
    for (int r = 0; r < 16; ++r)
        acc[r] = (rowmap(r, h) == m) ? 1.0f : 0.0f;
    f32x16 z;
#pragma unroll
    for (int i = 0; i < 16; ++i) z[i] = 0.f;

#pragma unroll
    for (int t = 0; t < L; ++t) {
        const float* Sb = (t & 1) ? S1 : S0;

        // counted wait: oldest 4 DMA ops (this step's matrix) retired; the
        // next matrix's 4 stay in flight. Only the last step drains fully.
        if (t < L - 1) { asm volatile("s_waitcnt vmcnt(4)" ::: "memory"); }
        else           { asm volatile("s_waitcnt vmcnt(0)" ::: "memory"); }

        // LDS -> regs: lanes 0-31 read consecutive dwords (conflict-free;
        // half-wave 2-way aliasing is free)
        float r_[16];
#pragma unroll
        for (int j = 0; j < 16; ++j)
            r_[j] = Sb[rowmap(j, h) * VV + m];

        // reads landed in regs -> safe to overwrite this buffer via DMA
        asm volatile("s_waitcnt lgkmcnt(0)" ::: "memory");
        if (t + 2 < L)
            stage_matrix(gbase + (size_t)(t + 2) * 1024, (t & 1) ? S1 : S0, lane);

        float e[16];
#pragma unroll
        for (int j = 0; j < 16; ++j)
            e[j] = __builtin_amdgcn_exp2f(__builtin_fmaf(r_[j], LOG2E, w2[j]));

        Frag a1, a2, b1, b2;
#pragma unroll
        for (int p = 0; p < 4; ++p) {
            a1.u[p] = pack_bf16(e[2 * p],       e[2 * p + 1]);
            a2.u[p] = pack_bf16(e[8 + 2 * p],   e[8 + 2 * p + 1]);
            b1.u[p] = pack_bf16(acc[2 * p],     acc[2 * p + 1]);
            b2.u[p] = pack_bf16(acc[8 + 2 * p], acc[8 + 2 * p + 1]);
        }
        f32x16 tmp = __builtin_amdgcn_mfma_f32_32x32x16_bf16(a1.v, b1.v, z,   0, 0, 0);
        acc        = __builtin_amdgcn_mfma_f32_32x32x16_bf16(a2.v, b2.v, tmp, 0, 0, 0);
    }

    // ---- in-block tree combine: P_total = (P3*P2)*(P1*P0) ----
    // pbuf aliases the (now fully drained) stage area.
    float* pb0 = smem;
    float* pb1 = smem + VV * PSTR;

    __syncthreads();   // all waves done reading their private stage buffers
    if (wid == 1) lds_export(pb0, m, h, acc);
    if (wid == 3) lds_export(pb1, m, h, acc);
    __syncthreads();
    if (wid == 0) acc = lds_mul(pb0, m, h, acc);   // P1*P0
    if (wid == 2) acc = lds_mul(pb1, m, h, acc);   // P3*P2
    if (wid == 3 && lane < 32) {
        // numerator partial for steps [q*32, q*32+32) — scores L2-hot here
        const int  t  = q * 32 + lane;
        const int* tg = targets + b * (TT + 1);
        const int  s_ = tg[t], d_ = tg[t + 1];
        const int  wi = s_ * VV + d_;
        float v = scores[((size_t)b * TT + t) * 1024 + wi] + w_tx[wi] + w_dur[wi];
#pragma unroll
        for (int mS = 16; mS >= 1; mS >>= 1) v += __shfl_xor(v, mS, 32);
        if (lane == 0) atomicAdd(out + b, v);
    }
    __syncthreads();
    if (wid == 2) lds_export(pb0, m, h, acc);
    __syncthreads();
    if (wid == 0) {
        acc = lds_mul(pb0, m, h, acc);             // (P3P2)*(P1P0)
        float* outP = ws_M + ((size_t)b * NMAT + q) * 1024;
#pragma unroll
        for (int r = 0; r < 16; ++r)
            outP[rowmap(r, h) * VV + m] = acc[r];
    }
}

__global__ __launch_bounds__(64) void crf_combine_kernel(
    const int*   __restrict__ targets,
    const float* __restrict__ w_init,
    const float* __restrict__ w_final,
    const float* __restrict__ ws_M,
    float* __restrict__ out)
{
    const int b    = blockIdx.x;
    const int lane = threadIdx.x;
    const int j    = lane & 31;

    float a    = __builtin_amdgcn_exp2f(w_init[j] * LOG2E);
    float accl = 0.f;
    const float* Pb = ws_M + (size_t)b * NMAT * 1024;

    float4 rr[8], rn[8];
#pragma unroll
    for (int qd = 0; qd < 8; ++qd) rr[qd] = *(const float4*)(Pb + j * VV + 4 * qd);

    for (int cI = 0; cI < NMAT; ++cI) {
        if (cI + 1 < NMAT) {
            const float* Pn = Pb + (size_t)(cI + 1) * 1024 + j * VV;
#pragma unroll
            for (int qd = 0; qd < 8; ++qd) rn[qd] = *(const float4*)(Pn + 4 * qd);
        }
        float an = 0.f;
#pragma unroll
        for (int i = 0; i < 32; ++i) {
            const float  ai = __shfl(a, i, 32);
            const float4 v  = rr[i >> 2];
            const float  pv = ((i & 3) == 0) ? v.x : ((i & 3) == 1) ? v.y
                             : ((i & 3) == 2) ? v.z : v.w;
            an = __builtin_fmaf(ai, pv, an);
        }
        float mx = an;
#pragma unroll
        for (int mS = 16; mS >= 1; mS >>= 1) mx = fmaxf(mx, __shfl_xor(mx, mS, 32));
        a = an / mx;
        accl += __builtin_amdgcn_logf(mx);   // log2
#pragma unroll
        for (int qd = 0; qd < 8; ++qd) rr[qd] = rn[qd];
    }

    float ss = a * __builtin_amdgcn_exp2f(w_final[j] * LOG2E);
#pragma unroll
    for (int mS = 16; mS >= 1; mS >>= 1) ss += __shfl_xor(ss, mS, 32);
    const float denom_ln =
        (__builtin_amdgcn_logf(ss) + accl + SHIFT * (float)TT) * LN2f;

    if (lane == 0) {
        const int* tg = targets + b * (TT + 1);
        atomicAdd(out + b, w_init[tg[0]] + w_final[tg[TT]] - denom_ln);
    }
}

extern "C" void kernel_launch(void* const* d_in, const int* in_sizes, int n_in,
                              void* d_out, int out_size, void* d_ws, size_t ws_size,
                              hipStream_t stream) {
    const float* scores  = (const float*)d_in[0];
    const int*   targets = (const int*)d_in[1];
    const float* w_tx    = (const float*)d_in[2];
    const float* w_init  = (const float*)d_in[3];
    const float* w_final = (const float*)d_in[4];
    const float* w_dur   = (const float*)d_in[5];
    float*       out     = (float*)d_out;
    float*       ws_M    = (float*)d_ws;   // BB*NMAT*4KB = 4 MiB

    hipMemsetAsync(out, 0, BB * sizeof(float), stream);
    crf_chunk_fused<<<BB * NMAT, 256, 0, stream>>>(scores, targets, w_tx, w_dur,
                                                   ws_M, out);
    crf_combine_kernel<<<BB, 64, 0, stream>>>(targets, w_init, w_final, ws_M, out);
}

// Round 2
// 208.340 us; speedup vs baseline: 1.0063x; 1.0038x over previous
//
#include <hip/hip_runtime.h>

// LatticeCrf log_prob on MI355X — MFMA chunked linear-space scan, v6.
// v6: dispatch-count reduction. The chunk kernel (HBM-roofline-bound at
// ~21 µs: must read 134 MB of scores once) is kept structurally as v5, but
// the numerator is moved into the combine kernel (waves 1-2 gather the 512
// target scores per b — L3-hot — while wave 0 runs the alpha scan). out[b]
// is written exactly once by a plain store: no memset dispatch, no atomics,
// no cross-dispatch read-modify-write ordering. 3 dispatches -> 2.
#define BB 64
#define TT 512
#define VV 32
#define CC 64           // chunks per sequence
#define L  8            // steps per chunk
#define QPB 4           // chunks per block (tree-combined)
#define NMAT (CC/QPB)   // 16 combined matrices per b
#define PSTR 34         // LDS pad stride for combine pbuf
#define LOG2E 1.4426950408889634f
#define LN2f  0.6931471805599453f
#define SHIFT 6.0f

typedef __bf16 bf16x8 __attribute__((ext_vector_type(8)));
typedef float  f32x16 __attribute__((ext_vector_type(16)));
union Frag { unsigned int u[4]; bf16x8 v; };

// round-half-up fp32->bf16 (inputs positive finite), pack two into one dword
__device__ __forceinline__ unsigned int pack_bf16(float lo, float hi) {
    unsigned int a = __float_as_uint(lo) + 0x8000u;
    unsigned int b = __float_as_uint(hi) + 0x8000u;
    return __builtin_amdgcn_perm(b, a, 0x07060302u); // [a.b2,a.b3,b.b2,b.b3]
}

// C-layout row for reg r / A-layout sigma for slot j: (x&3) + 8*(x>>2) + 4h
__device__ __forceinline__ int rowmap(int x, int h) {
    return (x & 3) + 8 * (x >> 2) + 4 * h;
}

// async global->LDS: 64 lanes x 16B = 1KB per instruction.
__device__ __forceinline__ void gload_lds_16(const void* g, const void* l) {
    __builtin_amdgcn_global_load_lds(
        (__attribute__((address_space(1))) void*)(uintptr_t)g,
        (__attribute__((address_space(3))) void*)(unsigned int)(uintptr_t)l,
        16, 0, 0);
}

// stage one 32x32 fp32 matrix (4KB, row-major, contiguous) into LDS linearly
__device__ __forceinline__ void stage_matrix(const float* g, float* l, int lane) {
#pragma unroll
    for (int i = 0; i < 4; ++i)
        gload_lds_16(g + i * 256 + lane * 4, l + i * 256);
}

// result = P_lds * accB   (A from LDS row-major stride PSTR, B = raw C-regs)
__device__ __forceinline__ f32x16 lds_mul(const float* P, int r, int h,
                                          const f32x16& accB) {
    Frag a1, a2, b1, b2;
#pragma unroll
    for (int p = 0; p < 4; ++p) {
        const int k1 = rowmap(2 * p, h);       // 0,2,8,10 (+4h)
        const int k2 = k1 + 16;
        const float2 x1 = *(const float2*)&P[r * PSTR + k1];
        const float2 x2 = *(const float2*)&P[r * PSTR + k2];
        a1.u[p] = pack_bf16(x1.x, x1.y);
        a2.u[p] = pack_bf16(x2.x, x2.y);
        b1.u[p] = pack_bf16(accB[2 * p],     accB[2 * p + 1]);
        b2.u[p] = pack_bf16(accB[8 + 2 * p], accB[8 + 2 * p + 1]);
    }
    f32x16 z;
#pragma unroll
    for (int i = 0; i < 16; ++i) z[i] = 0.f;
    f32x16 t = __builtin_amdgcn_mfma_f32_32x32x16_bf16(a1.v, b1.v, z, 0, 0, 0);
    return   __builtin_amdgcn_mfma_f32_32x32x16_bf16(a2.v, b2.v, t, 0, 0, 0);
}

__device__ __forceinline__ void lds_export(float* P, int m, int h,
                                           const f32x16& acc) {
#pragma unroll
    for (int r = 0; r < 16; ++r)
        P[rowmap(r, h) * PSTR + m] = acc[r];
}

__global__ __launch_bounds__(256, 4) void crf_chunk_fused(
    const float* __restrict__ scores,
    const float* __restrict__ w_tx,
    const float* __restrict__ w_dur,
    float* __restrict__ ws_M)
{
    // per-wave double-buffered score matrices (4 waves x 2 x 4KB = 32KB);
    // aliased as the combine pbuf after the main loop (all stages drained).
    __shared__ float smem[QPB * 2 * 1024];
    __shared__ float w2s[VV * VV];

    const int tid  = threadIdx.x;
    const int lane = tid & 63;
    const int wid  = tid >> 6;
    const int m    = lane & 31;
    const int h    = lane >> 5;
    const int b    = blockIdx.x >> 4;
    const int q    = blockIdx.x & 15;
    const int c    = q * QPB + wid;

    // stage w2 = (w_tx + w_dur)*log2e - SHIFT into LDS (1024 entries)
    {
        const float4 wt = *(const float4*)(w_tx  + tid * 4);
        const float4 wd = *(const float4*)(w_dur + tid * 4);
        float4 r;
        r.x = (wt.x + wd.x) * LOG2E - SHIFT;
        r.y = (wt.y + wd.y) * LOG2E - SHIFT;
        r.z = (wt.z + wd.z) * LOG2E - SHIFT;
        r.w = (wt.w + wd.w) * LOG2E - SHIFT;
        *(float4*)&w2s[tid * 4] = r;
    }
    __syncthreads();   // drains the wt/wd loads; DMA stages issue after this

    float* S0 = smem + wid * 2048;   // wave-private buffer 0 (1024 floats)
    float* S1 = S0 + 1024;           // wave-private buffer 1

    const float* gbase = scores + ((size_t)b * TT + (size_t)c * L) * 1024;

    // prologue: t0 -> S0, t1 -> S1 (8 global_load_lds in flight)
    stage_matrix(gbase,        S0, lane);
    stage_matrix(gbase + 1024, S1, lane);

    float w2[16];
#pragma unroll
    for (int j = 0; j < 16; ++j)
        w2[j] = w2s[rowmap(j, h) * VV + m];

    f32x16 acc;
#pragma unroll
    for (int r = 0; r < 16; ++r)
        acc[r] = (rowmap(r, h) == m) ? 1.0f : 0.0f;
    f32x16 z;
#pragma unroll
    for (int i = 0; i < 16; ++i) z[i] = 0.f;

#pragma unroll
    for (int t = 0; t < L; ++t) {
        const float* Sb = (t & 1) ? S1 : S0;

        // counted wait: oldest 4 DMA ops (this step's matrix) retired; the
        // next matrix's 4 stay in flight. Only the last step drains fully.
        if (t < L - 1) { asm volatile("s_waitcnt vmcnt(4)" ::: "memory"); }
        else           { asm volatile("s_waitcnt vmcnt(0)" ::: "memory"); }

        // LDS -> regs: lanes 0-31 read consecutive dwords (conflict-free;
        // half-wave 2-way aliasing is free)
        float r_[16];
#pragma unroll
        for (int j = 0; j < 16; ++j)
            r_[j] = Sb[rowmap(j, h) * VV + m];

        // reads landed in regs -> safe to overwrite this buffer via DMA
        asm volatile("s_waitcnt lgkmcnt(0)" ::: "memory");
        if (t + 2 < L)
            stage_matrix(gbase + (size_t)(t + 2) * 1024, (t & 1) ? S1 : S0, lane);

        float e[16];
#pragma unroll
        for (int j = 0; j < 16; ++j)
            e[j] = __builtin_amdgcn_exp2f(__builtin_fmaf(r_[j], LOG2E, w2[j]));

        Frag a1, a2, b1, b2;
#pragma unroll
        for (int p = 0; p < 4; ++p) {
            a1.u[p] = pack_bf16(e[2 * p],       e[2 * p + 1]);
            a2.u[p] = pack_bf16(e[8 + 2 * p],   e[8 + 2 * p + 1]);
            b1.u[p] = pack_bf16(acc[2 * p],     acc[2 * p + 1]);
            b2.u[p] = pack_bf16(acc[8 + 2 * p], acc[8 + 2 * p + 1]);
        }
        f32x16 tmp = __builtin_amdgcn_mfma_f32_32x32x16_bf16(a1.v, b1.v, z,   0, 0, 0);
        acc        = __builtin_amdgcn_mfma_f32_32x32x16_bf16(a2.v, b2.v, tmp, 0, 0, 0);
    }

    // ---- in-block tree combine: P_total = (P3*P2)*(P1*P0) ----
    // pbuf aliases the (now fully drained) stage area.
    float* pb0 = smem;
    float* pb1 = smem + VV * PSTR;

    __syncthreads();   // all waves done reading their private stage buffers
    if (wid == 1) lds_export(pb0, m, h, acc);
    if (wid == 3) lds_export(pb1, m, h, acc);
    __syncthreads();
    if (wid == 0) acc = lds_mul(pb0, m, h, acc);   // P1*P0
    if (wid == 2) acc = lds_mul(pb1, m, h, acc);   // P3*P2
    __syncthreads();
    if (wid == 2) lds_export(pb0, m, h, acc);
    __syncthreads();
    if (wid == 0) {
        acc = lds_mul(pb0, m, h, acc);             // (P3P2)*(P1P0)
        float* outP = ws_M + ((size_t)b * NMAT + q) * 1024;
#pragma unroll
        for (int r = 0; r < 16; ++r)
            outP[rowmap(r, h) * VV + m] = acc[r];
    }
}

__global__ __launch_bounds__(256) void crf_combine_kernel(
    const float* __restrict__ scores,
    const int*   __restrict__ targets,
    const float* __restrict__ w_tx,
    const float* __restrict__ w_init,
    const float* __restrict__ w_final,
    const float* __restrict__ w_dur,
    const float* __restrict__ ws_M,
    float* __restrict__ out)
{
    __shared__ float red[2];            // numerator partials from waves 1-2

    const int b    = blockIdx.x;
    const int tid  = threadIdx.x;
    const int wid  = tid >> 6;
    const int lane = tid & 63;
    const int* tg  = targets + b * (TT + 1);

    // ---- waves 1-2: numerator gather (512 terms over 128 lanes, L3-hot) ----
    if (wid == 1 || wid == 2) {
        const int u = tid - 64;          // 0..127
        float v = 0.f;
#pragma unroll
        for (int k = 0; k < 4; ++k) {
            const int t  = u + 128 * k;
            const int s_ = tg[t], d_ = tg[t + 1];
            const int wi = s_ * VV + d_;
            v += scores[((size_t)b * TT + t) * 1024 + wi] + w_tx[wi] + w_dur[wi];
        }
#pragma unroll
        for (int mS = 32; mS >= 1; mS >>= 1) v += __shfl_xor(v, mS, 64);
        if (lane == 0) red[wid - 1] = v;
    }

    // ---- wave 0: alpha scan over the 16 combined chunk matrices ----
    float denom_ln = 0.f;
    if (wid == 0) {
        const int j = lane & 31;
        float a    = __builtin_amdgcn_exp2f(w_init[j] * LOG2E);
        float accl = 0.f;
        const float* Pb = ws_M + (size_t)b * NMAT * 1024;

        float4 rr[8], rn[8];
#pragma unroll
        for (int qd = 0; qd < 8; ++qd)
            rr[qd] = *(const float4*)(Pb + j * VV + 4 * qd);

        for (int cI = 0; cI < NMAT; ++cI) {
            if (cI + 1 < NMAT) {
                const float* Pn = Pb + (size_t)(cI + 1) * 1024 + j * VV;
#pragma unroll
                for (int qd = 0; qd < 8; ++qd) rn[qd] = *(const float4*)(Pn + 4 * qd);
            }
            float an = 0.f;
#pragma unroll
            for (int i = 0; i < 32; ++i) {
                const float  ai = __shfl(a, i, 32);
                const float4 v  = rr[i >> 2];
                const float  pv = ((i & 3) == 0) ? v.x : ((i & 3) == 1) ? v.y
                                 : ((i & 3) == 2) ? v.z : v.w;
                an = __builtin_fmaf(ai, pv, an);
            }
            float mx = an;
#pragma unroll
            for (int mS = 16; mS >= 1; mS >>= 1) mx = fmaxf(mx, __shfl_xor(mx, mS, 32));
            a = an / mx;
            accl += __builtin_amdgcn_logf(mx);   // log2
#pragma unroll
            for (int qd = 0; qd < 8; ++qd) rr[qd] = rn[qd];
        }

        float ss = a * __builtin_amdgcn_exp2f(w_final[j] * LOG2E);
#pragma unroll
        for (int mS = 16; mS >= 1; mS >>= 1) ss += __shfl_xor(ss, mS, 32);
        denom_ln = (__builtin_amdgcn_logf(ss) + accl + SHIFT * (float)TT) * LN2f;
    }

    __syncthreads();
    if (tid == 0) {
        out[b] = red[0] + red[1] + w_init[tg[0]] + w_final[tg[TT]] - denom_ln;
    }
}

extern "C" void kernel_launch(void* const* d_in, const int* in_sizes, int n_in,
                              void* d_out, int out_size, void* d_ws, size_t ws_size,
                              hipStream_t stream) {
    const float* scores  = (const float*)d_in[0];
    const int*   targets = (const int*)d_in[1];
    const float* w_tx    = (const float*)d_in[2];
    const float* w_init  = (const float*)d_in[3];
    const float* w_final = (const float*)d_in[4];
    const float* w_dur   = (const float*)d_in[5];
    float*       out     = (float*)d_out;
    float*       ws_M    = (float*)d_ws;   // BB*NMAT*4KB = 4 MiB

    crf_chunk_fused<<<BB * NMAT, 256, 0, stream>>>(scores, w_tx, w_dur, ws_M);
    crf_combine_kernel<<<BB, 256, 0, stream>>>(scores, targets, w_tx, w_init,
                                               w_final, w_dur, ws_M, out);
}